// Round 18
// baseline (263.570 us; speedup 1.0000x reference)
//
#include <hip/hip_runtime.h>
#include <cstdint>
#include <cstddef>

typedef unsigned short u16;
typedef __attribute__((ext_vector_type(4))) float f32x4;
typedef __attribute__((ext_vector_type(16))) float f32x16;
typedef __attribute__((ext_vector_type(8))) _Float16 f16x8;
typedef __attribute__((ext_vector_type(4))) u16   u16x4;
typedef __attribute__((ext_vector_type(8))) u16   u16x8;
typedef __attribute__((ext_vector_type(4))) int   i32x4;

#define DEV static __device__ __forceinline__
#define MFMA16(a,b,c) __builtin_amdgcn_mfma_f32_16x16x32_f16((a),(b),(c),0,0,0)
#define MFMA32(a,b,c) __builtin_amdgcn_mfma_f32_32x32x16_f16((a),(b),(c),0,0,0)

constexpr int Bc = 4, Cc = 256, Nc = 2048, Hc = 8, Dc = 256, OCc = 2048;

constexpr size_t OFF_XT = 0;
constexpr size_t OFF_YT = OFF_XT + (size_t)Bc*Nc*Cc*2;
constexpr size_t OFF_WQ = OFF_YT + (size_t)Bc*Nc*Cc*2;
constexpr size_t OFF_WK = OFF_WQ + (size_t)OCc*Cc*2;
constexpr size_t OFF_WV = OFF_WK + (size_t)OCc*Cc*2;
constexpr size_t OFF_BQ = OFF_WV + (size_t)OCc*Cc*2;
constexpr size_t OFF_BK = OFF_BQ + (size_t)OCc*4;
constexpr size_t OFF_BV = OFF_BK + (size_t)OCc*4;
constexpr size_t OFF_Q  = OFF_BV + (size_t)OCc*4;              // (B,H,N,D) f16
constexpr size_t OFF_K  = OFF_Q  + (size_t)Bc*Hc*Nc*Dc*2;      // (B,H,N,D) f16
constexpr size_t OFF_V  = OFF_K  + (size_t)Bc*Hc*Nc*Dc*2;      // (B,H,D,N) f16 (V^T)

DEV u16 f2h(float x){
  _Float16 h = (_Float16)x;
  return __builtin_bit_cast(u16, h);
}

DEV void load_lds16(const void* g, void* l){
  __builtin_amdgcn_global_load_lds((const __attribute__((address_space(1))) int*)g,
                                   (__attribute__((address_space(3))) int*)l, 16, 0, 0);
}

// ---------------- kernel 0a: transpose + cast x,y -> X^T f16 (B,N,C) ----------------
__global__ __launch_bounds__(256) void transpose_cast(const float* __restrict__ x,
                                                      const float* __restrict__ y,
                                                      u16* __restrict__ XT,
                                                      u16* __restrict__ YT){
  __shared__ u16 tile[64][65];
  int b = blockIdx.z >> 1;
  const float* src = (blockIdx.z & 1) ? y : x;
  u16* dst = (blockIdx.z & 1) ? YT : XT;
  int n0 = blockIdx.x * 64, c0 = blockIdx.y * 64;
  int t = threadIdx.x;
#pragma unroll
  for (int i = 0; i < 16; ++i){
    int slot = i*256 + t;
    int cl = slot >> 6, nl = slot & 63;
    tile[cl][nl] = f2h(src[((size_t)b*Cc + c0 + cl)*Nc + n0 + nl]);
  }
  __syncthreads();
#pragma unroll
  for (int i = 0; i < 8; ++i){
    int slot = i*256 + t;
    int nl = slot >> 5, cl = (slot & 31)*2;
    uint32_t v = (uint32_t)tile[cl][nl] | ((uint32_t)tile[cl+1][nl] << 16);
    *(uint32_t*)(dst + ((size_t)b*Nc + n0 + nl)*Cc + c0 + cl) = v;
  }
}

// ---------------- kernel 0b: fused fold g into W (f16) for Q,K,V in one launch ----------------
__global__ __launch_bounds__(256) void prep_w3(
    const float* __restrict__ W0, const float* __restrict__ b0,
    const float* __restrict__ g0, const float* __restrict__ be0,
    const float* __restrict__ W1, const float* __restrict__ b1,
    const float* __restrict__ g1, const float* __restrict__ be1,
    const float* __restrict__ W2, const float* __restrict__ b2,
    const float* __restrict__ g2, const float* __restrict__ be2,
    u16* __restrict__ Wo0, float* __restrict__ bb0,
    u16* __restrict__ Wo1, float* __restrict__ bb1,
    u16* __restrict__ Wo2, float* __restrict__ bb2){
  int which = blockIdx.y;
  const float* W  = (which == 0) ? W0  : (which == 1) ? W1  : W2;
  const float* bs = (which == 0) ? b0  : (which == 1) ? b1  : b2;
  const float* g  = (which == 0) ? g0  : (which == 1) ? g1  : g2;
  const float* be = (which == 0) ? be0 : (which == 1) ? be1 : be2;
  u16*   Wo = (which == 0) ? Wo0 : (which == 1) ? Wo1 : Wo2;
  float* bb = (which == 0) ? bb0 : (which == 1) ? bb1 : bb2;

  int idx = (blockIdx.x*256 + threadIdx.x) * 8;
  int o = idx >> 8, c = idx & 255;
  float gg = g[o];
  f32x4 a0 = *(const f32x4*)(W + idx);
  f32x4 a1 = *(const f32x4*)(W + idx + 4);
  u16x8 r;
#pragma unroll
  for (int i = 0; i < 4; ++i){ r[i] = f2h(a0[i]*gg); r[i+4] = f2h(a1[i]*gg); }
  *(u16x8*)(Wo + idx) = r;
  if (c == 0) bb[o] = gg*bs[o] + be[o];
}

// ---------------- kernel 1a: fused Q+K projection (SW=0 body, R14-exact inner loop) ----------------
// grid (16,16,8): fid selects (bx, by, zz); zz&3 = batch, zz>>2 = {0:Q, 1:K}. 2048%8==0 bijective.
__global__ __launch_bounds__(256, 2) void proj_qk(const u16* __restrict__ XT,
                                                  const u16* __restrict__ YT,
                                                  const u16* __restrict__ WQ,
                                                  const u16* __restrict__ WK,
                                                  const float* __restrict__ BQ,
                                                  const float* __restrict__ BK,
                                                  u16* __restrict__ Qw,
                                                  u16* __restrict__ Kw){
  __shared__ __align__(16) char lds[32768];
  int t = threadIdx.x, w = t >> 6, l = t & 63, q = l & 15, g = l >> 4;

  const int hid = blockIdx.x + 16*blockIdx.y + 256*blockIdx.z;   // 0..2047
  const int fid = (hid & 7)*256 + (hid >> 3);                    // bijective
  const int bx = fid & 15, by = (fid >> 4) & 15, zz = fid >> 8;  // zz 0..7
  const int b = zz & 3, sel = zz >> 2;
  const u16* Xt = sel ? YT : XT;
  const u16* Wp = sel ? WK : WQ;
  const float* bb = sel ? BK : BQ;
  u16* outp = sel ? Kw : Qw;
  int n0 = bx * 128, o0 = by * 128;

  int fs = ((q >> 1) & 3) << 4;
  int partg = ((l & 3) ^ ((l >> 3) & 3));
  f32x4 acc[4][4] = {};

  for (int it = 0; it < 4; ++it){
    __syncthreads();
#pragma unroll
    for (int j = 0; j < 8; ++j){
      int s = j*4 + w;
      int chunk = s >> 3;
      int off = (s & 7) * 1024;
      int row = (s & 7)*16 + (l >> 2);
      const char* gsrc;
      if (chunk < 2)
        gsrc = (const char*)(Wp + (size_t)(o0 + row)*Cc) + it*128 + chunk*64 + partg*16;
      else
        gsrc = (const char*)(Xt + ((size_t)b*Nc + n0 + row)*Cc) + it*128 + (chunk & 1)*64 + partg*16;
      load_lds16(gsrc, lds + chunk*8192 + off);
    }
    asm volatile("s_waitcnt vmcnt(0)" ::: "memory");
    __syncthreads();
#pragma unroll
    for (int kc = 0; kc < 2; ++kc){
      f16x8 fw[4], fx[4];
#pragma unroll
      for (int i = 0; i < 4; ++i){
        int wrow = (w >> 1)*64 + i*16 + q;
        int xrow = (w & 1)*64 + i*16 + q;
        fw[i] = *(const f16x8*)(lds + kc*8192 + wrow*64 + ((g*16) ^ fs));
        fx[i] = *(const f16x8*)(lds + 16384 + kc*8192 + xrow*64 + ((g*16) ^ fs));
      }
#pragma unroll
      for (int i = 0; i < 4; ++i)
#pragma unroll
        for (int jj = 0; jj < 4; ++jj)
          acc[i][jj] = MFMA16(fw[i], fx[jj], acc[i][jj]);
    }
  }

  f32x4 bias[4];
#pragma unroll
  for (int i = 0; i < 4; ++i) bias[i] = *(const f32x4*)(bb + o0 + (w>>1)*64 + i*16 + 4*g);
#pragma unroll
  for (int i = 0; i < 4; ++i)
#pragma unroll
    for (int jj = 0; jj < 4; ++jj){
      u16x4 pk;
#pragma unroll
      for (int r = 0; r < 4; ++r){
        float z = acc[i][jj][r] + bias[i][r];
        pk[r] = f2h(fmaxf(z, 0.f));
      }
      int o = o0 + (w>>1)*64 + i*16 + 4*g;
      int n = n0 + (w&1)*64 + jj*16 + q;
      int hh = o >> 8, d = o & 255;
      *(u16x4*)(outp + ((size_t)((b*Hc + hh)*Nc + n))*Dc + d) = pk;
    }
}

// ---------------- kernel 1b: V projection (R17-exact: SW=1 body + XCD swizzle) ----------------
__global__ __launch_bounds__(256, 2) void proj_v(const u16* __restrict__ Xt,
                                                 const u16* __restrict__ Wp,
                                                 const float* __restrict__ bb,
                                                 u16* __restrict__ outp){
  __shared__ __align__(16) char lds[32768];
  int t = threadIdx.x, w = t >> 6, l = t & 63, q = l & 15, g = l >> 4;

  const int hid = blockIdx.x + 16*blockIdx.y + 256*blockIdx.z;   // 0..1023
  const int fid = (hid & 7)*128 + (hid >> 3);                    // bijective
  const int bx = fid & 15, by = (fid >> 4) & 15, b = fid >> 8;
  int n0 = bx * 128, o0 = by * 128;

  int fs = ((q >> 1) & 3) << 4;
  int partg = ((l & 3) ^ ((l >> 3) & 3));
  f32x4 acc[4][4] = {};

  for (int it = 0; it < 4; ++it){
    __syncthreads();
#pragma unroll
    for (int j = 0; j < 8; ++j){
      int s = j*4 + w;
      int chunk = s >> 3;
      int off = (s & 7) * 1024;
      int row = (s & 7)*16 + (l >> 2);
      const char* gsrc;
      if (chunk < 2)
        gsrc = (const char*)(Wp + (size_t)(o0 + row)*Cc) + it*128 + chunk*64 + partg*16;
      else
        gsrc = (const char*)(Xt + ((size_t)b*Nc + n0 + row)*Cc) + it*128 + (chunk & 1)*64 + partg*16;
      load_lds16(gsrc, lds + chunk*8192 + off);
    }
    asm volatile("s_waitcnt vmcnt(0)" ::: "memory");
    __syncthreads();
#pragma unroll
    for (int kc = 0; kc < 2; ++kc){
      f16x8 fw[4], fx[4];
#pragma unroll
      for (int i = 0; i < 4; ++i){
        int wrow = (w & 1)*64 + i*16 + q;
        int xrow = (w >> 1)*64 + i*16 + q;
        fw[i] = *(const f16x8*)(lds + kc*8192 + wrow*64 + ((g*16) ^ fs));
        fx[i] = *(const f16x8*)(lds + 16384 + kc*8192 + xrow*64 + ((g*16) ^ fs));
      }
#pragma unroll
      for (int i = 0; i < 4; ++i)
#pragma unroll
        for (int jj = 0; jj < 4; ++jj)
          acc[i][jj] = MFMA16(fx[i], fw[jj], acc[i][jj]);
    }
  }

  float biasv[4];
#pragma unroll
  for (int i = 0; i < 4; ++i) biasv[i] = bb[o0 + (w&1)*64 + i*16 + q];
#pragma unroll
  for (int i = 0; i < 4; ++i)
#pragma unroll
    for (int jj = 0; jj < 4; ++jj){
      u16x4 pk;
#pragma unroll
      for (int r = 0; r < 4; ++r){
        float z = acc[i][jj][r] + biasv[jj];
        pk[r] = f2h(fmaxf(z, 0.f));
      }
      int o = o0 + (w&1)*64 + jj*16 + q;
      int n = n0 + (w>>1)*64 + i*16 + 4*g;
      int hh = o >> 8, d = o & 255;
      *(u16x4*)(outp + ((size_t)((b*Hc + hh)*Dc + d))*Nc + n) = pk;
    }
}

// ---------------- kernel 2: flash attention (R16/R17-EXACT — best verified, 201us) ----------------
__global__ __launch_bounds__(512, 1) void attn_kernel(const u16* __restrict__ Qp,
                                                      const u16* __restrict__ Kp,
                                                      const u16* __restrict__ Vp,
                                                      float* __restrict__ outp){
  __shared__ __align__(16) char lds[150528];
  const int t = threadIdx.x, w = t >> 6, l = t & 63, lq = l & 31, hi = l >> 5;
  const int wq = w & 3, wm = w >> 2;

  // XCD-aware swizzle: hardware dispatch id -> work id (chunked per XCD)
  const int hid = blockIdx.x + 16*blockIdx.y + 128*blockIdx.z;   // 0..511, x fastest
  const int fid = (hid & 7)*64 + (hid >> 3);                     // bijective chunk map
  const int bx = fid & 15, h = (fid >> 4) & 7, b = fid >> 7;
  const int q0 = bx * 128;

  size_t head = (size_t)(b*Hc + h) * Nc * Dc;
  const u16* Qh = Qp + head;
  const u16* Kh = Kp + head;
  const u16* Vh = Vp + head;

  char* Pex  = lds + 131072;              // 16KB: [w][2 frags][lane*16B]
  float* smax = (float*)(lds + 147456);   // 8 strips x 32
  float* ssum = (float*)(lds + 148480);

  // Q B-frags: lane(lq,hi) holds Q[q0+wq*32+lq][kc*16 + hi*8 + e]
  f16x8 qf[16];
  {
    const u16* qrow = Qh + (size_t)(q0 + wq*32 + lq) * Dc;
#pragma unroll
    for (int kc = 0; kc < 16; ++kc) qf[kc] = *(const f16x8*)(qrow + kc*16 + hi*8);
  }

  f32x16 acc[4] = {};                     // O[32q rows][d-half wm: 4 dt x 32 cols]
  float m_run = -1e30f, l_run = 0.f;
  const int lsw = lq ^ ((lq >> 3) & 3);   // K read-side scramble (0 real conflicts)

  // staging: K 8w*4j*2rows=64 rows (512B, 5-bit scramble); V 8w*4j*8rows=256 (128B rows)
#define STAGE_KV(m0_, buf_)                                                        \
  {                                                                                \
    char* Kd = lds + (buf_)*32768;                                                 \
    char* Vd = lds + 65536 + (buf_)*32768;                                         \
    _Pragma("unroll")                                                              \
    for (int j = 0; j < 4; ++j){                                                   \
      int row = w*8 + j*2 + hi;                                                    \
      int r5 = row & 31;                                                           \
      int gs = (l & 31) ^ r5 ^ ((r5 >> 3) & 3);                                    \
      load_lds16(Kh + (size_t)((m0_) + row)*Dc + gs*8, Kd + w*4096 + j*1024);      \
    }                                                                              \
    _Pragma("unroll")                                                              \
    for (int j = 0; j < 4; ++j){                                                   \
      int ri = w*4 + j;                                                            \
      int rd = ri*8 + (l >> 3);                                                    \
      int gs = (l & 7) ^ (rd & 7);                                                 \
      load_lds16(Vh + (size_t)rd*Nc + (m0_) + gs*8, Vd + ri*1024);                 \
    }                                                                              \
  }

  STAGE_KV(0, 0);
  asm volatile("s_waitcnt vmcnt(0)" ::: "memory");
  __syncthreads();

  for (int it = 0; it < 32; ++it){
    const int cur = it & 1;
    char* Kc = lds + cur*32768;
    char* Vc = lds + 65536 + cur*32768;

    if (it < 31) STAGE_KV((it + 1)*64, cur ^ 1);

    // QK^T: S^T[strip wm][group wq], A=K-strip, B=Q
    f32x16 s = {};
    __builtin_amdgcn_s_setprio(1);
#pragma unroll
    for (int kc = 0; kc < 16; ++kc){
      f16x8 kf = *(const f16x8*)(Kc + (wm*32 + lq)*512 + (((kc*2 + hi) ^ lsw) << 4));
      s = MFMA32(kf, qf[kc], s);
    }
    __builtin_amdgcn_s_setprio(0);

    // strip max (16 in-lane + hi partner)
    float tmax = s[0];
#pragma unroll
    for (int r = 1; r < 16; ++r) tmax = fmaxf(tmax, s[r]);
    tmax = fmaxf(tmax, __shfl_xor(tmax, 32));
    if (!hi) smax[(wq*2 + wm)*32 + lq] = tmax;
    __syncthreads();                                           // B2
    float omax = smax[(wq*2 + (1 - wm))*32 + lq];
    float cmax = fmaxf(tmax, omax);

    // T13 defer-max: decision identical across the wm pair (cmax symmetric, m_run shared)
    float meff = m_run, scale = 1.f;
    const bool need = !__all(cmax <= m_run + 8.f);
    if (need){
      meff = fmaxf(m_run, cmax);
      scale = __expf(m_run - meff);
      m_run = meff;
    }

    float p[16];
    float rsum = 0.f;
#pragma unroll
    for (int r = 0; r < 16; ++r){ p[r] = __expf(s[r] - meff); rsum += p[r]; }
    rsum += __shfl_xor(rsum, 32);
    if (!hi) ssum[(wq*2 + wm)*32 + lq] = rsum;

    // pack P to f16; build own-strip A-frags (k-in-frag = hi*8+e)
    int pk[8];
#pragma unroll
    for (int j2 = 0; j2 < 8; ++j2)
      pk[j2] = __builtin_bit_cast(int, __builtin_amdgcn_cvt_pkrtz(p[2*j2], p[2*j2+1]));
    int sx[8];
#pragma unroll
    for (int j2 = 0; j2 < 8; ++j2) sx[j2] = __shfl_xor(pk[j2], 32);
    i32x4 f0, f1;
    f0[0] = hi ? sx[2] : pk[0];  f0[1] = hi ? sx[3] : pk[1];
    f0[2] = hi ? pk[2] : sx[0];  f0[3] = hi ? pk[3] : sx[1];
    f1[0] = hi ? sx[6] : pk[4];  f1[1] = hi ? sx[7] : pk[5];
    f1[2] = hi ? pk[6] : sx[4];  f1[3] = hi ? pk[7] : sx[5];
    *(i32x4*)(Pex + w*2048 + l*16)        = f0;
    *(i32x4*)(Pex + w*2048 + 1024 + l*16) = f1;
    __syncthreads();                                           // B3

    float osum = ssum[(wq*2 + (1 - wm))*32 + lq];
    l_run = l_run * scale + rsum + osum;

    // rescale acc only when max moved (shfl broadcast, no LDS)
    if (need){
#pragma unroll
      for (int r = 0; r < 16; ++r){
        float scr = __shfl(scale, (r & 3) + 8*(r >> 2) + 4*hi);
#pragma unroll
        for (int dt = 0; dt < 4; ++dt) acc[dt][r] *= scr;
      }
    }

    i32x4 g0 = *(const i32x4*)(Pex + (w ^ 4)*2048 + l*16);
    i32x4 g1 = *(const i32x4*)(Pex + (w ^ 4)*2048 + 1024 + l*16);
    f16x8 a0 = __builtin_bit_cast(f16x8, wm ? g0 : f0);   // m 0..15
    f16x8 a1 = __builtin_bit_cast(f16x8, wm ? g1 : f1);   // m 16..31
    f16x8 a2 = __builtin_bit_cast(f16x8, wm ? f0 : g0);   // m 32..47
    f16x8 a3 = __builtin_bit_cast(f16x8, wm ? f1 : g1);   // m 48..63

    // PV: O[32q][d-half] += P · V^T ; V rows 128B, slot = h2*4+mcl*2+hi
    __builtin_amdgcn_s_setprio(1);
#pragma unroll
    for (int h2 = 0; h2 < 2; ++h2)
#pragma unroll
      for (int dt = 0; dt < 4; ++dt)
#pragma unroll
        for (int mcl = 0; mcl < 2; ++mcl){
          f16x8 vf = *(const f16x8*)(Vc + (wm*128 + dt*32 + lq)*128 +
                                     (((h2*4 + mcl*2 + hi)*16) ^ ((l & 7) << 4)));
          f16x8 af = h2 ? (mcl ? a3 : a2) : (mcl ? a1 : a0);
          acc[dt] = MFMA32(af, vf, acc[dt]);
        }
    __builtin_amdgcn_s_setprio(0);

    // drain next-tile stage loads; release buffers
    asm volatile("s_waitcnt vmcnt(0)" ::: "memory");
    __syncthreads();                                           // B1
  }
#undef STAGE_KV

  // epilogue: l_run identical across hi and the wm pair -> in-wave shfl broadcast
  float inv_own = 1.f / l_run;
#pragma unroll
  for (int r = 0; r < 16; ++r){
    int crow = (r & 3) + 8*(r >> 2) + 4*hi;
    float invr = __shfl(inv_own, crow);
    size_t obase = head + (size_t)(q0 + wq*32 + crow)*Dc + wm*128 + lq;
#pragma unroll
    for (int dt = 0; dt < 4; ++dt)
      outp[obase + dt*32] = acc[dt][r] * invr;
  }
}

// ---------------- launch ----------------
extern "C" void kernel_launch(void* const* d_in, const int* in_sizes, int n_in,
                              void* d_out, int out_size, void* d_ws, size_t ws_size,
                              hipStream_t stream){
  const float* x     = (const float*)d_in[0];
  const float* y     = (const float*)d_in[1];
  const float* Wq    = (const float*)d_in[2];
  const float* bq    = (const float*)d_in[3];
  const float* gq    = (const float*)d_in[4];
  const float* betaq = (const float*)d_in[5];
  const float* Wk    = (const float*)d_in[6];
  const float* bk    = (const float*)d_in[7];
  const float* gk    = (const float*)d_in[8];
  const float* betak = (const float*)d_in[9];
  const float* Wv    = (const float*)d_in[10];
  const float* bv    = (const float*)d_in[11];
  const float* gv    = (const float*)d_in[12];
  const float* betav = (const float*)d_in[13];
  char* ws = (char*)d_ws;
  float* outp = (float*)d_out;

  u16* XT = (u16*)(ws + OFF_XT);
  u16* YT = (u16*)(ws + OFF_YT);
  u16* WQb = (u16*)(ws + OFF_WQ);
  u16* WKb = (u16*)(ws + OFF_WK);
  u16* WVb = (u16*)(ws + OFF_WV);
  float* BQ = (float*)(ws + OFF_BQ);
  float* BK = (float*)(ws + OFF_BK);
  float* BV = (float*)(ws + OFF_BV);
  u16* Qw = (u16*)(ws + OFF_Q);
  u16* Kw = (u16*)(ws + OFF_K);
  u16* Vw = (u16*)(ws + OFF_V);

  transpose_cast<<<dim3(Nc/64, Cc/64, Bc*2), 256, 0, stream>>>(x, y, XT, YT);
  prep_w3<<<dim3(OCc*Cc/2048, 3), 256, 0, stream>>>(
      Wq, bq, gq, betaq, Wk, bk, gk, betak, Wv, bv, gv, betav,
      WQb, BQ, WKb, BK, WVb, BV);

  proj_qk<<<dim3(Nc/128, OCc/128, 2*Bc), 256, 0, stream>>>(XT, YT, WQb, WKb, BQ, BK, Qw, Kw);
  proj_v<<<dim3(Nc/128, OCc/128, Bc), 256, 0, stream>>>(YT, WVb, BV, Vw);

  attn_kernel<<<dim3(Nc/128, Hc, Bc), 512, 0, stream>>>(Qw, Kw, Vw, outp);
}

// Round 19
// 259.522 us; speedup vs baseline: 1.0156x; 1.0156x over previous
//
#include <hip/hip_runtime.h>
#include <cstdint>
#include <cstddef>

typedef unsigned short u16;
typedef __attribute__((ext_vector_type(4))) float f32x4;
typedef __attribute__((ext_vector_type(16))) float f32x16;
typedef __attribute__((ext_vector_type(8))) _Float16 f16x8;
typedef __attribute__((ext_vector_type(4))) u16   u16x4;
typedef __attribute__((ext_vector_type(8))) u16   u16x8;
typedef __attribute__((ext_vector_type(4))) int   i32x4;

#define DEV static __device__ __forceinline__
#define MFMA16(a,b,c) __builtin_amdgcn_mfma_f32_16x16x32_f16((a),(b),(c),0,0,0)
#define MFMA32(a,b,c) __builtin_amdgcn_mfma_f32_32x32x16_f16((a),(b),(c),0,0,0)

constexpr int Bc = 4, Cc = 256, Nc = 2048, Hc = 8, Dc = 256, OCc = 2048;

constexpr size_t OFF_XT = 0;
constexpr size_t OFF_YT = OFF_XT + (size_t)Bc*Nc*Cc*2;
constexpr size_t OFF_WQ = OFF_YT + (size_t)Bc*Nc*Cc*2;
constexpr size_t OFF_WK = OFF_WQ + (size_t)OCc*Cc*2;
constexpr size_t OFF_WV = OFF_WK + (size_t)OCc*Cc*2;
constexpr size_t OFF_BQ = OFF_WV + (size_t)OCc*Cc*2;
constexpr size_t OFF_BK = OFF_BQ + (size_t)OCc*4;
constexpr size_t OFF_BV = OFF_BK + (size_t)OCc*4;
constexpr size_t OFF_Q  = OFF_BV + (size_t)OCc*4;              // (B,H,N,D) f16
constexpr size_t OFF_K  = OFF_Q  + (size_t)Bc*Hc*Nc*Dc*2;      // (B,H,N,D) f16
constexpr size_t OFF_V  = OFF_K  + (size_t)Bc*Hc*Nc*Dc*2;      // (B,H,D,N) f16 (V^T)

DEV u16 f2h(float x){
  _Float16 h = (_Float16)x;
  return __builtin_bit_cast(u16, h);
}

DEV void load_lds16(const void* g, void* l){
  __builtin_amdgcn_global_load_lds((const __attribute__((address_space(1))) int*)g,
                                   (__attribute__((address_space(3))) int*)l, 16, 0, 0);
}

// ---------------- kernel 0a: transpose + cast x,y -> X^T f16 (B,N,C) ----------------
__global__ __launch_bounds__(256) void transpose_cast(const float* __restrict__ x,
                                                      const float* __restrict__ y,
                                                      u16* __restrict__ XT,
                                                      u16* __restrict__ YT){
  __shared__ u16 tile[64][65];
  int b = blockIdx.z >> 1;
  const float* src = (blockIdx.z & 1) ? y : x;
  u16* dst = (blockIdx.z & 1) ? YT : XT;
  int n0 = blockIdx.x * 64, c0 = blockIdx.y * 64;
  int t = threadIdx.x;
#pragma unroll
  for (int i = 0; i < 16; ++i){
    int slot = i*256 + t;
    int cl = slot >> 6, nl = slot & 63;
    tile[cl][nl] = f2h(src[((size_t)b*Cc + c0 + cl)*Nc + n0 + nl]);
  }
  __syncthreads();
#pragma unroll
  for (int i = 0; i < 8; ++i){
    int slot = i*256 + t;
    int nl = slot >> 5, cl = (slot & 31)*2;
    uint32_t v = (uint32_t)tile[cl][nl] | ((uint32_t)tile[cl+1][nl] << 16);
    *(uint32_t*)(dst + ((size_t)b*Nc + n0 + nl)*Cc + c0 + cl) = v;
  }
}

// ---------------- kernel 0b: fold g into W (f16), bias = g*b+beta (R14-exact) ----------------
__global__ __launch_bounds__(256) void prep_w(const float* __restrict__ W,
                                              const float* __restrict__ bsrc,
                                              const float* __restrict__ g,
                                              const float* __restrict__ beta,
                                              u16* __restrict__ Wo,
                                              float* __restrict__ bb){
  int idx = (blockIdx.x*256 + threadIdx.x) * 8;
  int o = idx >> 8, c = idx & 255;
  float gg = g[o];
  f32x4 a0 = *(const f32x4*)(W + idx);
  f32x4 a1 = *(const f32x4*)(W + idx + 4);
  u16x8 r;
#pragma unroll
  for (int i = 0; i < 4; ++i){ r[i] = f2h(a0[i]*gg); r[i+4] = f2h(a1[i]*gg); }
  *(u16x8*)(Wo + idx) = r;
  if (c == 0) bb[o] = gg*bsrc[o] + beta[o];
}

// ---------------- kernel 1: projection GEMM (R14-exact body + XCD-chunked swizzle) ----------------
template<int SW>
__global__ __launch_bounds__(256, 2) void proj_gemm(const u16* __restrict__ Xt,
                                                    const u16* __restrict__ Wp,
                                                    const float* __restrict__ bb,
                                                    u16* __restrict__ outp){
  __shared__ __align__(16) char lds[32768];
  int t = threadIdx.x, w = t >> 6, l = t & 63, q = l & 15, g = l >> 4;

  // XCD-aware chunked swizzle
  const int hid = blockIdx.x + 16*blockIdx.y + 256*blockIdx.z;   // 0..1023
  const int fid = (hid & 7)*128 + (hid >> 3);                    // bijective
  const int bx = fid & 15, by = (fid >> 4) & 15, b = fid >> 8;
  int n0 = bx * 128, o0 = by * 128;

  int fs = ((q >> 1) & 3) << 4;
  int partg = ((l & 3) ^ ((l >> 3) & 3));
  f32x4 acc[4][4] = {};

  for (int it = 0; it < 4; ++it){
    __syncthreads();
#pragma unroll
    for (int j = 0; j < 8; ++j){
      int s = j*4 + w;
      int chunk = s >> 3;
      int off = (s & 7) * 1024;
      int row = (s & 7)*16 + (l >> 2);
      const char* gsrc;
      if (chunk < 2)
        gsrc = (const char*)(Wp + (size_t)(o0 + row)*Cc) + it*128 + chunk*64 + partg*16;
      else
        gsrc = (const char*)(Xt + ((size_t)b*Nc + n0 + row)*Cc) + it*128 + (chunk & 1)*64 + partg*16;
      load_lds16(gsrc, lds + chunk*8192 + off);
    }
    asm volatile("s_waitcnt vmcnt(0)" ::: "memory");
    __syncthreads();
#pragma unroll
    for (int kc = 0; kc < 2; ++kc){
      f16x8 fw[4], fx[4];
#pragma unroll
      for (int i = 0; i < 4; ++i){
        int wrow = (SW ? (w & 1) : (w >> 1))*64 + i*16 + q;
        int xrow = (SW ? (w >> 1) : (w & 1))*64 + i*16 + q;
        fw[i] = *(const f16x8*)(lds + kc*8192 + wrow*64 + ((g*16) ^ fs));
        fx[i] = *(const f16x8*)(lds + 16384 + kc*8192 + xrow*64 + ((g*16) ^ fs));
      }
#pragma unroll
      for (int i = 0; i < 4; ++i)
#pragma unroll
        for (int jj = 0; jj < 4; ++jj){
          if constexpr (!SW) acc[i][jj] = MFMA16(fw[i], fx[jj], acc[i][jj]);
          else               acc[i][jj] = MFMA16(fx[i], fw[jj], acc[i][jj]);
        }
    }
  }

  if constexpr (!SW) {
    f32x4 bias[4];
#pragma unroll
    for (int i = 0; i < 4; ++i) bias[i] = *(const f32x4*)(bb + o0 + (w>>1)*64 + i*16 + 4*g);
#pragma unroll
    for (int i = 0; i < 4; ++i)
#pragma unroll
      for (int jj = 0; jj < 4; ++jj){
        u16x4 pk;
#pragma unroll
        for (int r = 0; r < 4; ++r){
          float z = acc[i][jj][r] + bias[i][r];
          pk[r] = f2h(fmaxf(z, 0.f));
        }
        int o = o0 + (w>>1)*64 + i*16 + 4*g;
        int n = n0 + (w&1)*64 + jj*16 + q;
        int hh = o >> 8, d = o & 255;
        *(u16x4*)(outp + ((size_t)((b*Hc + hh)*Nc + n))*Dc + d) = pk;
      }
  } else {
    float biasv[4];
#pragma unroll
    for (int i = 0; i < 4; ++i) biasv[i] = bb[o0 + (w&1)*64 + i*16 + q];
#pragma unroll
    for (int i = 0; i < 4; ++i)
#pragma unroll
      for (int jj = 0; jj < 4; ++jj){
        u16x4 pk;
#pragma unroll
        for (int r = 0; r < 4; ++r){
          float z = acc[i][jj][r] + biasv[jj];
          pk[r] = f2h(fmaxf(z, 0.f));
        }
        int o = o0 + (w&1)*64 + jj*16 + q;
        int n = n0 + (w>>1)*64 + i*16 + 4*g;
        int hh = o >> 8, d = o & 255;
        *(u16x4*)(outp + ((size_t)((b*Hc + hh)*Dc + d))*Nc + n) = pk;
      }
  }
}

// ---------------- kernel 2: flash attention (R16/R17-EXACT — best verified, 201us) ----------------
__global__ __launch_bounds__(512, 1) void attn_kernel(const u16* __restrict__ Qp,
                                                      const u16* __restrict__ Kp,
                                                      const u16* __restrict__ Vp,
                                                      float* __restrict__ outp){
  __shared__ __align__(16) char lds[150528];
  const int t = threadIdx.x, w = t >> 6, l = t & 63, lq = l & 31, hi = l >> 5;
  const int wq = w & 3, wm = w >> 2;

  // XCD-aware swizzle: hardware dispatch id -> work id (chunked per XCD)
  const int hid = blockIdx.x + 16*blockIdx.y + 128*blockIdx.z;   // 0..511, x fastest
  const int fid = (hid & 7)*64 + (hid >> 3);                     // bijective chunk map
  const int bx = fid & 15, h = (fid >> 4) & 7, b = fid >> 7;
  const int q0 = bx * 128;

  size_t head = (size_t)(b*Hc + h) * Nc * Dc;
  const u16* Qh = Qp + head;
  const u16* Kh = Kp + head;
  const u16* Vh = Vp + head;

  char* Pex  = lds + 131072;              // 16KB: [w][2 frags][lane*16B]
  float* smax = (float*)(lds + 147456);   // 8 strips x 32
  float* ssum = (float*)(lds + 148480);

  // Q B-frags: lane(lq,hi) holds Q[q0+wq*32+lq][kc*16 + hi*8 + e]
  f16x8 qf[16];
  {
    const u16* qrow = Qh + (size_t)(q0 + wq*32 + lq) * Dc;
#pragma unroll
    for (int kc = 0; kc < 16; ++kc) qf[kc] = *(const f16x8*)(qrow + kc*16 + hi*8);
  }

  f32x16 acc[4] = {};                     // O[32q rows][d-half wm: 4 dt x 32 cols]
  float m_run = -1e30f, l_run = 0.f;
  const int lsw = lq ^ ((lq >> 3) & 3);   // K read-side scramble (0 real conflicts)

  // staging: K 8w*4j*2rows=64 rows (512B, 5-bit scramble); V 8w*4j*8rows=256 (128B rows)
#define STAGE_KV(m0_, buf_)                                                        \
  {                                                                                \
    char* Kd = lds + (buf_)*32768;                                                 \
    char* Vd = lds + 65536 + (buf_)*32768;                                         \
    _Pragma("unroll")                                                              \
    for (int j = 0; j < 4; ++j){                                                   \
      int row = w*8 + j*2 + hi;                                                    \
      int r5 = row & 31;                                                           \
      int gs = (l & 31) ^ r5 ^ ((r5 >> 3) & 3);                                    \
      load_lds16(Kh + (size_t)((m0_) + row)*Dc + gs*8, Kd + w*4096 + j*1024);      \
    }                                                                              \
    _Pragma("unroll")                                                              \
    for (int j = 0; j < 4; ++j){                                                   \
      int ri = w*4 + j;                                                            \
      int rd = ri*8 + (l >> 3);                                                    \
      int gs = (l & 7) ^ (rd & 7);                                                 \
      load_lds16(Vh + (size_t)rd*Nc + (m0_) + gs*8, Vd + ri*1024);                 \
    }                                                                              \
  }

  STAGE_KV(0, 0);
  asm volatile("s_waitcnt vmcnt(0)" ::: "memory");
  __syncthreads();

  for (int it = 0; it < 32; ++it){
    const int cur = it & 1;
    char* Kc = lds + cur*32768;
    char* Vc = lds + 65536 + cur*32768;

    if (it < 31) STAGE_KV((it + 1)*64, cur ^ 1);

    // QK^T: S^T[strip wm][group wq], A=K-strip, B=Q
    f32x16 s = {};
    __builtin_amdgcn_s_setprio(1);
#pragma unroll
    for (int kc = 0; kc < 16; ++kc){
      f16x8 kf = *(const f16x8*)(Kc + (wm*32 + lq)*512 + (((kc*2 + hi) ^ lsw) << 4));
      s = MFMA32(kf, qf[kc], s);
    }
    __builtin_amdgcn_s_setprio(0);

    // strip max (16 in-lane + hi partner)
    float tmax = s[0];
#pragma unroll
    for (int r = 1; r < 16; ++r) tmax = fmaxf(tmax, s[r]);
    tmax = fmaxf(tmax, __shfl_xor(tmax, 32));
    if (!hi) smax[(wq*2 + wm)*32 + lq] = tmax;
    __syncthreads();                                           // B2
    float omax = smax[(wq*2 + (1 - wm))*32 + lq];
    float cmax = fmaxf(tmax, omax);

    // T13 defer-max: decision identical across the wm pair (cmax symmetric, m_run shared)
    float meff = m_run, scale = 1.f;
    const bool need = !__all(cmax <= m_run + 8.f);
    if (need){
      meff = fmaxf(m_run, cmax);
      scale = __expf(m_run - meff);
      m_run = meff;
    }

    float p[16];
    float rsum = 0.f;
#pragma unroll
    for (int r = 0; r < 16; ++r){ p[r] = __expf(s[r] - meff); rsum += p[r]; }
    rsum += __shfl_xor(rsum, 32);
    if (!hi) ssum[(wq*2 + wm)*32 + lq] = rsum;

    // pack P to f16; build own-strip A-frags (k-in-frag = hi*8+e)
    int pk[8];
#pragma unroll
    for (int j2 = 0; j2 < 8; ++j2)
      pk[j2] = __builtin_bit_cast(int, __builtin_amdgcn_cvt_pkrtz(p[2*j2], p[2*j2+1]));
    int sx[8];
#pragma unroll
    for (int j2 = 0; j2 < 8; ++j2) sx[j2] = __shfl_xor(pk[j2], 32);
    i32x4 f0, f1;
    f0[0] = hi ? sx[2] : pk[0];  f0[1] = hi ? sx[3] : pk[1];
    f0[2] = hi ? pk[2] : sx[0];  f0[3] = hi ? pk[3] : sx[1];
    f1[0] = hi ? sx[6] : pk[4];  f1[1] = hi ? sx[7] : pk[5];
    f1[2] = hi ? pk[6] : sx[4];  f1[3] = hi ? pk[7] : sx[5];
    *(i32x4*)(Pex + w*2048 + l*16)        = f0;
    *(i32x4*)(Pex + w*2048 + 1024 + l*16) = f1;
    __syncthreads();                                           // B3

    float osum = ssum[(wq*2 + (1 - wm))*32 + lq];
    l_run = l_run * scale + rsum + osum;

    // rescale acc only when max moved (shfl broadcast, no LDS)
    if (need){
#pragma unroll
      for (int r = 0; r < 16; ++r){
        float scr = __shfl(scale, (r & 3) + 8*(r >> 2) + 4*hi);
#pragma unroll
        for (int dt = 0; dt < 4; ++dt) acc[dt][r] *= scr;
      }
    }

    i32x4 g0 = *(const i32x4*)(Pex + (w ^ 4)*2048 + l*16);
    i32x4 g1 = *(const i32x4*)(Pex + (w ^ 4)*2048 + 1024 + l*16);
    f16x8 a0 = __builtin_bit_cast(f16x8, wm ? g0 : f0);   // m 0..15
    f16x8 a1 = __builtin_bit_cast(f16x8, wm ? g1 : f1);   // m 16..31
    f16x8 a2 = __builtin_bit_cast(f16x8, wm ? f0 : g0);   // m 32..47
    f16x8 a3 = __builtin_bit_cast(f16x8, wm ? f1 : g1);   // m 48..63

    // PV: O[32q][d-half] += P · V^T ; V rows 128B, slot = h2*4+mcl*2+hi
    __builtin_amdgcn_s_setprio(1);
#pragma unroll
    for (int h2 = 0; h2 < 2; ++h2)
#pragma unroll
      for (int dt = 0; dt < 4; ++dt)
#pragma unroll
        for (int mcl = 0; mcl < 2; ++mcl){
          f16x8 vf = *(const f16x8*)(Vc + (wm*128 + dt*32 + lq)*128 +
                                     (((h2*4 + mcl*2 + hi)*16) ^ ((l & 7) << 4)));
          f16x8 af = h2 ? (mcl ? a3 : a2) : (mcl ? a1 : a0);
          acc[dt] = MFMA32(af, vf, acc[dt]);
        }
    __builtin_amdgcn_s_setprio(0);

    // drain next-tile stage loads; release buffers
    asm volatile("s_waitcnt vmcnt(0)" ::: "memory");
    __syncthreads();                                           // B1
  }
#undef STAGE_KV

  // epilogue: l_run identical across hi and the wm pair -> in-wave shfl broadcast
  float inv_own = 1.f / l_run;
#pragma unroll
  for (int r = 0; r < 16; ++r){
    int crow = (r & 3) + 8*(r >> 2) + 4*hi;
    float invr = __shfl(inv_own, crow);
    size_t obase = head + (size_t)(q0 + wq*32 + crow)*Dc + wm*128 + lq;
#pragma unroll
    for (int dt = 0; dt < 4; ++dt)
      outp[obase + dt*32] = acc[dt][r] * invr;
  }
}

// ---------------- launch ----------------
extern "C" void kernel_launch(void* const* d_in, const int* in_sizes, int n_in,
                              void* d_out, int out_size, void* d_ws, size_t ws_size,
                              hipStream_t stream){
  const float* x     = (const float*)d_in[0];
  const float* y     = (const float*)d_in[1];
  const float* Wq    = (const float*)d_in[2];
  const float* bq    = (const float*)d_in[3];
  const float* gq    = (const float*)d_in[4];
  const float* betaq = (const float*)d_in[5];
  const float* Wk    = (const float*)d_in[6];
  const float* bk    = (const float*)d_in[7];
  const float* gk    = (const float*)d_in[8];
  const float* betak = (const float*)d_in[9];
  const float* Wv    = (const float*)d_in[10];
  const float* bv    = (const float*)d_in[11];
  const float* gv    = (const float*)d_in[12];
  const float* betav = (const float*)d_in[13];
  char* ws = (char*)d_ws;
  float* outp = (float*)d_out;

  u16* XT = (u16*)(ws + OFF_XT);
  u16* YT = (u16*)(ws + OFF_YT);
  u16* WQb = (u16*)(ws + OFF_WQ);
  u16* WKb = (u16*)(ws + OFF_WK);
  u16* WVb = (u16*)(ws + OFF_WV);
  float* BQ = (float*)(ws + OFF_BQ);
  float* BK = (float*)(ws + OFF_BK);
  float* BV = (float*)(ws + OFF_BV);
  u16* Qw = (u16*)(ws + OFF_Q);
  u16* Kw = (u16*)(ws + OFF_K);
  u16* Vw = (u16*)(ws + OFF_V);

  transpose_cast<<<dim3(Nc/64, Cc/64, Bc*2), 256, 0, stream>>>(x, y, XT, YT);
  prep_w<<<dim3(OCc*Cc/2048), 256, 0, stream>>>(Wq, bq, gq, betaq, WQb, BQ);
  prep_w<<<dim3(OCc*Cc/2048), 256, 0, stream>>>(Wk, bk, gk, betak, WKb, BK);
  prep_w<<<dim3(OCc*Cc/2048), 256, 0, stream>>>(Wv, bv, gv, betav, WVb, BV);

  dim3 pg(Nc/128, OCc/128, Bc);
  proj_gemm<0><<<pg, 256, 0, stream>>>(XT, WQb, BQ, Qw);
  proj_gemm<0><<<pg, 256, 0, stream>>>(YT, WKb, BK, Kw);
  proj_gemm<1><<<pg, 256, 0, stream>>>(YT, WVb, BV, Vw);

  attn_kernel<<<dim3(Nc/128, Hc, Bc), 512, 0, stream>>>(Qw, Kw, Vw, outp);
}